// Round 4
// baseline (936.654 us; speedup 1.0000x reference)
//
#include <hip/hip_runtime.h>
#include <math.h>

#define N_NODES 50000
#define N_EDGES 800000
#define EPS 1e-12f

// ---------------- K0: per-node precompute ----------------
__global__ void k_node_init(const float* __restrict__ X, const float* __restrict__ yp,
                            float4* __restrict__ px4, float* __restrict__ f) {
    int n = blockIdx.x * blockDim.x + threadIdx.x;
    if (n < N_NODES) {
        px4[n] = make_float4(X[n * 6 + 0], X[n * 6 + 1], X[n * 6 + 2], X[n * 6 + 4]);
        f[n] = yp[n];
    }
}

// ---------------- K1: per-edge precompute ----------------
__global__ void k_edge_init(const int* __restrict__ edge,
                            const float4* __restrict__ px4,
                            const float* __restrict__ yp,
                            int2* __restrict__ sd, float4* __restrict__ dnrm,
                            float4* __restrict__ ea, float* __restrict__ cnt) {
    int e = blockIdx.x * blockDim.x + threadIdx.x;
    if (e < N_EDGES) {
        int s = edge[e];
        int d = edge[N_EDGES + e];
        sd[e] = make_int2(s, d);
        float4 ps = px4[s], pd = px4[d];
        float dx = pd.x - ps.x, dy = pd.y - ps.y, dz = pd.z - ps.z;
        float nrm = sqrtf(dx * dx + dy * dy + dz * dz + EPS);
        dnrm[e] = make_float4(dx, dy, dz, nrm);
        float fr = yp[d] - yp[s];
        ea[e] = make_float4(fr * dx, fr * dy, fr * dz, 0.f);
        atomicAdd(&cnt[d], 1.0f);
    }
}

// ---------------- K2: edge MLP + scatter-add ----------------
// All array-indexing loops FULLY unrolled (constant indices -> SROA promotes,
// no scratch). launch_bounds(256,2) -> 256-VGPR budget, no spill.
// Peak live set: h1[64] + acc[16] + misc ~ 110 VGPRs.
__global__ __launch_bounds__(256, 2) void k_edge_mlp(
    const int2* __restrict__ sd, const float4* __restrict__ dnrm,
    float4* __restrict__ ea, const float* __restrict__ f,
    const float* __restrict__ ew1, const float* __restrict__ eb1,
    const float* __restrict__ ew2, const float* __restrict__ eb2,
    const float* __restrict__ ew3, const float* __restrict__ eb3,
    float* __restrict__ aggr) {
    int e = blockIdx.x * blockDim.x + threadIdx.x;
    if (e >= N_EDGES) return;

    int2 SD = sd[e];
    float4 DN = dnrm[e];
    float4 EA = ea[e];
    float fs = f[SD.x], fd = f[SD.y];

    float in9[9] = {DN.x, DN.y, DN.z, DN.w, EA.x, EA.y, EA.z, fs, fd};

    // layer 1: h1[64] = relu(in9 @ ew1 + eb1)
    float h1[64];
#pragma unroll
    for (int i = 0; i < 64; i++) {
        float a = eb1[i];
#pragma unroll
        for (int k = 0; k < 9; k++) a += ew1[k * 64 + i] * in9[k];
        h1[i] = fmaxf(a, 0.f);
    }

    // layer 2 (chunked 4x16) fused with layer 3
    float o0 = eb3[0], o1 = eb3[1], o2 = eb3[2];
#pragma unroll
    for (int jc = 0; jc < 4; jc++) {
        float acc[16];
#pragma unroll
        for (int j = 0; j < 16; j++) acc[j] = eb2[jc * 16 + j];
#pragma unroll
        for (int i = 0; i < 64; i++) {
#pragma unroll
            for (int j = 0; j < 16; j++) acc[j] += h1[i] * ew2[i * 64 + jc * 16 + j];
        }
#pragma unroll
        for (int j = 0; j < 16; j++) {
            float r = fmaxf(acc[j], 0.f);
            int jj = jc * 16 + j;
            o0 += r * ew3[jj * 3 + 0];
            o1 += r * ew3[jj * 3 + 1];
            o2 += r * ew3[jj * 3 + 2];
        }
    }

    float r0 = EA.x + o0, r1 = EA.y + o1, r2 = EA.z + o2;
    ea[e] = make_float4(r0, r1, r2, 0.f);
    atomicAdd(&aggr[SD.y * 3 + 0], r0);
    atomicAdd(&aggr[SD.y * 3 + 1], r1);
    atomicAdd(&aggr[SD.y * 3 + 2], r2);
}

// ---------------- K3: node MLP, f += delta ----------------
__global__ __launch_bounds__(256, 2) void k_node_mlp(
    const float4* __restrict__ px4, float* __restrict__ f,
    const float* __restrict__ aggr, const float* __restrict__ cnt,
    const float* __restrict__ nw1, const float* __restrict__ nb1,
    const float* __restrict__ nw2, const float* __restrict__ nb2,
    const float* __restrict__ nw3, const float* __restrict__ nb3) {
    int n = blockIdx.x * blockDim.x + threadIdx.x;
    if (n >= N_NODES) return;

    float inv = 1.0f / fmaxf(cnt[n], 1.0f);
    float4 P = px4[n];
    float fn = f[n];
    float in5[5] = {P.w, fn, aggr[n * 3 + 0] * inv, aggr[n * 3 + 1] * inv,
                    aggr[n * 3 + 2] * inv};

    float h1[64];
#pragma unroll
    for (int i = 0; i < 64; i++) {
        float a = nb1[i];
#pragma unroll
        for (int k = 0; k < 5; k++) a += nw1[k * 64 + i] * in5[k];
        h1[i] = fmaxf(a, 0.f);
    }

    float o = nb3[0];
#pragma unroll
    for (int jc = 0; jc < 4; jc++) {
        float acc[16];
#pragma unroll
        for (int j = 0; j < 16; j++) acc[j] = nb2[jc * 16 + j];
#pragma unroll
        for (int i = 0; i < 64; i++) {
#pragma unroll
            for (int j = 0; j < 16; j++) acc[j] += h1[i] * nw2[i * 64 + jc * 16 + j];
        }
#pragma unroll
        for (int j = 0; j < 16; j++) o += fmaxf(acc[j], 0.f) * nw3[jc * 16 + j];
    }
    f[n] = fn + o;
}

// ---------------- K4: decoder + residual ----------------
__global__ __launch_bounds__(256, 2) void k_decoder(
    const float4* __restrict__ px4, const float* __restrict__ f,
    const float* __restrict__ yp,
    const float* __restrict__ dw1, const float* __restrict__ db1,
    const float* __restrict__ dw2, const float* __restrict__ db2,
    const float* __restrict__ dw3, const float* __restrict__ db3,
    const float* __restrict__ dw4, const float* __restrict__ db4,
    float* __restrict__ out) {
    int n = blockIdx.x * blockDim.x + threadIdx.x;
    if (n >= N_NODES) return;

    float4 P = px4[n];
    float fn = f[n];
    float in5[5] = {P.x, P.y, P.z, P.w, fn};

    float h1[64];
#pragma unroll
    for (int i = 0; i < 64; i++) {
        float a = db1[i];
#pragma unroll
        for (int k = 0; k < 5; k++) a += dw1[k * 64 + i] * in5[k];
        h1[i] = fmaxf(a, 0.f);
    }

    // layer 2 -> h2[64] (chunked; h2 written with constant indices)
    float h2[64];
#pragma unroll
    for (int jc = 0; jc < 4; jc++) {
        float acc[16];
#pragma unroll
        for (int j = 0; j < 16; j++) acc[j] = db2[jc * 16 + j];
#pragma unroll
        for (int i = 0; i < 64; i++) {
#pragma unroll
            for (int j = 0; j < 16; j++) acc[j] += h1[i] * dw2[i * 64 + jc * 16 + j];
        }
#pragma unroll
        for (int j = 0; j < 16; j++) h2[jc * 16 + j] = fmaxf(acc[j], 0.f);
    }

    // layer 3 fused with output dot
    float o = db4[0];
#pragma unroll
    for (int jc = 0; jc < 4; jc++) {
        float acc[16];
#pragma unroll
        for (int j = 0; j < 16; j++) acc[j] = db3[jc * 16 + j];
#pragma unroll
        for (int i = 0; i < 64; i++) {
#pragma unroll
            for (int j = 0; j < 16; j++) acc[j] += h2[i] * dw3[i * 64 + jc * 16 + j];
        }
#pragma unroll
        for (int j = 0; j < 16; j++) o += fmaxf(acc[j], 0.f) * dw4[jc * 16 + j];
    }
    out[n] = yp[n] + o;
}

extern "C" void kernel_launch(void* const* d_in, const int* in_sizes, int n_in,
                              void* d_out, int out_size, void* d_ws, size_t ws_size,
                              hipStream_t stream) {
    const float* X    = (const float*)d_in[0];
    const float* yp   = (const float*)d_in[1];
    const int*   edge = (const int*)d_in[2];
    const float *ew1 = (const float*)d_in[3],  *eb1 = (const float*)d_in[4];
    const float *ew2 = (const float*)d_in[5],  *eb2 = (const float*)d_in[6];
    const float *ew3 = (const float*)d_in[7],  *eb3 = (const float*)d_in[8];
    const float *nw1 = (const float*)d_in[9],  *nb1 = (const float*)d_in[10];
    const float *nw2 = (const float*)d_in[11], *nb2 = (const float*)d_in[12];
    const float *nw3 = (const float*)d_in[13], *nb3 = (const float*)d_in[14];
    const float *dw1 = (const float*)d_in[15], *db1 = (const float*)d_in[16];
    const float *dw2 = (const float*)d_in[17], *db2 = (const float*)d_in[18];
    const float *dw3 = (const float*)d_in[19], *db3 = (const float*)d_in[20];
    const float *dw4 = (const float*)d_in[21], *db4 = (const float*)d_in[22];
    float* out = (float*)d_out;

    char* p = (char*)d_ws;
    auto carve = [&](size_t bytes) {
        char* r = p;
        p += (bytes + 255) & ~(size_t)255;
        return r;
    };
    int2*   sd   = (int2*)  carve(sizeof(int2)   * N_EDGES);
    float4* dnrm = (float4*)carve(sizeof(float4) * N_EDGES);
    float4* ea   = (float4*)carve(sizeof(float4) * N_EDGES);
    float4* px4  = (float4*)carve(sizeof(float4) * N_NODES);
    float*  f    = (float*) carve(sizeof(float)  * N_NODES);
    float*  cnt  = (float*) carve(sizeof(float)  * N_NODES);
    float*  aggr = (float*) carve(sizeof(float)  * 3 * N_NODES);

    const int nb_n = (N_NODES + 255) / 256;
    const int nb_e = (N_EDGES + 255) / 256;

    hipMemsetAsync(cnt, 0, sizeof(float) * N_NODES, stream);
    k_node_init<<<nb_n, 256, 0, stream>>>(X, yp, px4, f);
    k_edge_init<<<nb_e, 256, 0, stream>>>(edge, px4, yp, sd, dnrm, ea, cnt);

    for (int it = 0; it < 3; ++it) {
        hipMemsetAsync(aggr, 0, sizeof(float) * 3 * N_NODES, stream);
        k_edge_mlp<<<nb_e, 256, 0, stream>>>(sd, dnrm, ea, f,
                                             ew1, eb1, ew2, eb2, ew3, eb3, aggr);
        k_node_mlp<<<nb_n, 256, 0, stream>>>(px4, f, aggr, cnt,
                                             nw1, nb1, nw2, nb2, nw3, nb3);
    }
    k_decoder<<<nb_n, 256, 0, stream>>>(px4, f, yp,
                                        dw1, db1, dw2, db2, dw3, db3, dw4, db4, out);
}

// Round 5
// 759.902 us; speedup vs baseline: 1.2326x; 1.2326x over previous
//
#include <hip/hip_runtime.h>
#include <math.h>

#define N_NODES 50000
#define N_EDGES 800000
#define EPS 1e-12f

typedef __attribute__((ext_vector_type(8))) short bf16x8;
typedef __attribute__((ext_vector_type(4))) float f32x4;

__device__ inline unsigned pk_bf16(float a, float b) {
    unsigned ua = __float_as_uint(a), ub = __float_as_uint(b);
    ua = (ua + 0x7FFFu + ((ua >> 16) & 1u)) >> 16;
    ub = (ub + 0x7FFFu + ((ub >> 16) & 1u)) >> 16;
    return ua | (ub << 16);
}
__device__ inline unsigned short bf16_1(float a) {
    unsigned ua = __float_as_uint(a);
    return (unsigned short)((ua + 0x7FFFu + ((ua >> 16) & 1u)) >> 16);
}

// ---------------- K0: per-node precompute ----------------
__global__ void k_node_init(const float* __restrict__ X, const float* __restrict__ yp,
                            float4* __restrict__ px4, float* __restrict__ f) {
    int n = blockIdx.x * blockDim.x + threadIdx.x;
    if (n < N_NODES) {
        px4[n] = make_float4(X[n * 6 + 0], X[n * 6 + 1], X[n * 6 + 2], X[n * 6 + 4]);
        f[n] = yp[n];
    }
}

// ---------------- K1: per-edge precompute ----------------
__global__ void k_edge_init(const int* __restrict__ edge,
                            const float4* __restrict__ px4,
                            const float* __restrict__ yp,
                            int2* __restrict__ sd, float4* __restrict__ dnrm,
                            float4* __restrict__ ea, float* __restrict__ cnt) {
    int e = blockIdx.x * blockDim.x + threadIdx.x;
    if (e < N_EDGES) {
        int s = edge[e];
        int d = edge[N_EDGES + e];
        sd[e] = make_int2(s, d);
        float4 ps = px4[s], pd = px4[d];
        float dx = pd.x - ps.x, dy = pd.y - ps.y, dz = pd.z - ps.z;
        float nrm = sqrtf(dx * dx + dy * dy + dz * dz + EPS);
        dnrm[e] = make_float4(dx, dy, dz, nrm);
        float fr = yp[d] - yp[s];
        ea[e] = make_float4(fr * dx, fr * dy, fr * dz, 0.f);
        atomicAdd(&cnt[d], 1.0f);
    }
}

// ---------------- K2: edge MLP via bf16 MFMA ----------------
// Block = 256 thr (4 waves), each wave owns 64 edges in a private LDS buffer
// (stride 144 B/row: 64 ch bf16 = 128 B + 16 B out-pad; 16B-aligned frags).
// MFMA 16x16x32 bf16: A[m=lane&15][k=quad*8+j], B[k][n=lane&15], C col=lane&15,
// row=quad*4+reg (m89/m91-verified mappings).
#define W1OFF 0
#define W2OFF 4096
#define W3OFF 13312
#define BUFOFF 15616
#define RS 144  // row stride (bytes) for wave buffers / W2T / W3T

__global__ __launch_bounds__(256, 2) void k_edge_mlp(
    const int2* __restrict__ sd, const float4* __restrict__ dnrm,
    float4* __restrict__ ea, const float* __restrict__ f,
    const float* __restrict__ ew1, const float* __restrict__ eb1,
    const float* __restrict__ ew2, const float* __restrict__ eb2,
    const float* __restrict__ ew3, const float* __restrict__ eb3,
    float* __restrict__ aggr) {
    __shared__ __align__(16) char smem[15616 + 4 * 64 * RS];
    const int t = threadIdx.x;
    const int lane = t & 63, wave = t >> 6;
    const int c = lane & 15, q = lane >> 4;

    // ---- stage W1T[64n][32k] (stride 64B), W2T[64n][64k] (stride 144B),
    //      W3T[16n][64k] (stride 144B) as bf16 ----
    {
        int n = t & 63, kg = t >> 6;  // kg 0..3
        unsigned pk[4];
#pragma unroll
        for (int i = 0; i < 4; i++) {
            int k0 = kg * 8 + i * 2;
            float v0 = (k0 < 9) ? ew1[k0 * 64 + n] : 0.f;
            float v1 = (k0 + 1 < 9) ? ew1[(k0 + 1) * 64 + n] : 0.f;
            pk[i] = pk_bf16(v0, v1);
        }
        *(uint4*)(smem + W1OFF + n * 64 + kg * 16) =
            make_uint4(pk[0], pk[1], pk[2], pk[3]);

        unsigned pk2[8];
#pragma unroll
        for (int i = 0; i < 8; i++) {
            int k0 = kg * 16 + i * 2;
            pk2[i] = pk_bf16(ew2[k0 * 64 + n], ew2[(k0 + 1) * 64 + n]);
        }
        *(uint4*)(smem + W2OFF + n * RS + kg * 32) =
            make_uint4(pk2[0], pk2[1], pk2[2], pk2[3]);
        *(uint4*)(smem + W2OFF + n * RS + kg * 32 + 16) =
            make_uint4(pk2[4], pk2[5], pk2[6], pk2[7]);

        int n3 = t & 15, kg3 = t >> 4;  // kg3 0..15, k = kg3*4 + i
        unsigned pk3[2];
#pragma unroll
        for (int i = 0; i < 2; i++) {
            int k0 = kg3 * 4 + i * 2;
            float v0 = (n3 < 3) ? ew3[k0 * 3 + n3] : 0.f;
            float v1 = (n3 < 3) ? ew3[(k0 + 1) * 3 + n3] : 0.f;
            pk3[i] = pk_bf16(v0, v1);
        }
        *(uint2*)(smem + W3OFF + n3 * RS + kg3 * 8) = make_uint2(pk3[0], pk3[1]);
    }

    // ---- phase A: per-lane edge gather, in9 -> LDS rows (k padded to 32) ----
    char* mybuf = smem + BUFOFF + wave * (64 * RS);
    const int e = blockIdx.x * 256 + t;
    int2 SD = sd[e];
    float4 DN = dnrm[e];
    float4 EA = ea[e];
    float fs = f[SD.x], fd = f[SD.y];
    {
        char* row = mybuf + lane * RS;
        *(uint4*)(row) = make_uint4(pk_bf16(DN.x, DN.y), pk_bf16(DN.z, DN.w),
                                    pk_bf16(EA.x, EA.y), pk_bf16(EA.z, fs));
        *(uint4*)(row + 16) = make_uint4(pk_bf16(fd, 0.f), 0u, 0u, 0u);
        *(uint4*)(row + 32) = make_uint4(0u, 0u, 0u, 0u);
        *(uint4*)(row + 48) = make_uint4(0u, 0u, 0u, 0u);
    }
    __syncthreads();

    // ---- GEMM1: [64e,32k] x [32k,64n] ----
    {
        bf16x8 A1[4], B1[4];
#pragma unroll
        for (int mt = 0; mt < 4; mt++)
            A1[mt] = *(bf16x8*)(mybuf + (mt * 16 + c) * RS + q * 16);
#pragma unroll
        for (int nt = 0; nt < 4; nt++)
            B1[nt] = *(bf16x8*)(smem + W1OFF + (nt * 16 + c) * 64 + q * 16);
        f32x4 acc[16];
#pragma unroll
        for (int nt = 0; nt < 4; nt++) {
            float b = eb1[nt * 16 + c];
#pragma unroll
            for (int mt = 0; mt < 4; mt++) acc[mt * 4 + nt] = (f32x4){b, b, b, b};
        }
#pragma unroll
        for (int mt = 0; mt < 4; mt++)
#pragma unroll
            for (int nt = 0; nt < 4; nt++)
                acc[mt * 4 + nt] = __builtin_amdgcn_mfma_f32_16x16x32_bf16(
                    A1[mt], B1[nt], acc[mt * 4 + nt], 0, 0, 0);
        // relu -> bf16 -> H1[edge][ch] (overwrites IN region; A1 already read)
#pragma unroll
        for (int mt = 0; mt < 4; mt++)
#pragma unroll
            for (int nt = 0; nt < 4; nt++)
#pragma unroll
                for (int r = 0; r < 4; r++)
                    *(unsigned short*)(mybuf + (mt * 16 + q * 4 + r) * RS +
                                       (nt * 16 + c) * 2) =
                        bf16_1(fmaxf(acc[mt * 4 + nt][r], 0.f));
    }

    // ---- GEMM2 (64k, 2 K-steps) + GEMM3 fused per M-tile ----
    bf16x8 B2[8], B3[2];
#pragma unroll
    for (int nt = 0; nt < 4; nt++)
#pragma unroll
        for (int ks = 0; ks < 2; ks++)
            B2[nt * 2 + ks] =
                *(bf16x8*)(smem + W2OFF + (nt * 16 + c) * RS + ks * 64 + q * 16);
#pragma unroll
    for (int ks = 0; ks < 2; ks++)
        B3[ks] = *(bf16x8*)(smem + W3OFF + c * RS + ks * 64 + q * 16);
    float b3i = (c < 3) ? eb3[c] : 0.f;

#pragma unroll
    for (int mt = 0; mt < 4; mt++) {
        bf16x8 A2[2];
#pragma unroll
        for (int ks = 0; ks < 2; ks++)
            A2[ks] = *(bf16x8*)(mybuf + (mt * 16 + c) * RS + ks * 64 + q * 16);
        f32x4 a2[4];
#pragma unroll
        for (int nt = 0; nt < 4; nt++) {
            float b = eb2[nt * 16 + c];
            a2[nt] = (f32x4){b, b, b, b};
            a2[nt] = __builtin_amdgcn_mfma_f32_16x16x32_bf16(A2[0], B2[nt * 2 + 0],
                                                             a2[nt], 0, 0, 0);
            a2[nt] = __builtin_amdgcn_mfma_f32_16x16x32_bf16(A2[1], B2[nt * 2 + 1],
                                                             a2[nt], 0, 0, 0);
        }
        // relu -> bf16 -> H2 (same band, after A2 reads)
#pragma unroll
        for (int nt = 0; nt < 4; nt++)
#pragma unroll
            for (int r = 0; r < 4; r++)
                *(unsigned short*)(mybuf + (mt * 16 + q * 4 + r) * RS +
                                   (nt * 16 + c) * 2) =
                    bf16_1(fmaxf(a2[nt][r], 0.f));
        // GEMM3: [16e,64k] x [64k,16n(3 valid)]
        bf16x8 A3[2];
#pragma unroll
        for (int ks = 0; ks < 2; ks++)
            A3[ks] = *(bf16x8*)(mybuf + (mt * 16 + c) * RS + ks * 64 + q * 16);
        f32x4 a3 = (f32x4){b3i, b3i, b3i, b3i};
        a3 = __builtin_amdgcn_mfma_f32_16x16x32_bf16(A3[0], B3[0], a3, 0, 0, 0);
        a3 = __builtin_amdgcn_mfma_f32_16x16x32_bf16(A3[1], B3[1], a3, 0, 0, 0);
        if (c < 3) {
#pragma unroll
            for (int r = 0; r < 4; r++)
                *(float*)(mybuf + (mt * 16 + q * 4 + r) * RS + 128 + c * 4) = a3[r];
        }
    }

    // ---- epilogue: residual + store + scatter-add (per-lane edge) ----
    float4 o = *(float4*)(mybuf + lane * RS + 128);
    float r0 = EA.x + o.x, r1 = EA.y + o.y, r2 = EA.z + o.z;
    ea[e] = make_float4(r0, r1, r2, 0.f);
    atomicAdd(&aggr[SD.y * 3 + 0], r0);
    atomicAdd(&aggr[SD.y * 3 + 1], r1);
    atomicAdd(&aggr[SD.y * 3 + 2], r2);
}

// ---------------- K3: node MLP, f += delta ----------------
__global__ __launch_bounds__(256, 2) void k_node_mlp(
    const float4* __restrict__ px4, float* __restrict__ f,
    const float* __restrict__ aggr, const float* __restrict__ cnt,
    const float* __restrict__ nw1, const float* __restrict__ nb1,
    const float* __restrict__ nw2, const float* __restrict__ nb2,
    const float* __restrict__ nw3, const float* __restrict__ nb3) {
    int n = blockIdx.x * blockDim.x + threadIdx.x;
    if (n >= N_NODES) return;

    float inv = 1.0f / fmaxf(cnt[n], 1.0f);
    float4 P = px4[n];
    float fn = f[n];
    float in5[5] = {P.w, fn, aggr[n * 3 + 0] * inv, aggr[n * 3 + 1] * inv,
                    aggr[n * 3 + 2] * inv};

    float h1[64];
#pragma unroll
    for (int i = 0; i < 64; i++) {
        float a = nb1[i];
#pragma unroll
        for (int k = 0; k < 5; k++) a += nw1[k * 64 + i] * in5[k];
        h1[i] = fmaxf(a, 0.f);
    }

    float o = nb3[0];
#pragma unroll
    for (int jc = 0; jc < 4; jc++) {
        float acc[16];
#pragma unroll
        for (int j = 0; j < 16; j++) acc[j] = nb2[jc * 16 + j];
#pragma unroll
        for (int i = 0; i < 64; i++) {
#pragma unroll
            for (int j = 0; j < 16; j++) acc[j] += h1[i] * nw2[i * 64 + jc * 16 + j];
        }
#pragma unroll
        for (int j = 0; j < 16; j++) o += fmaxf(acc[j], 0.f) * nw3[jc * 16 + j];
    }
    f[n] = fn + o;
}

// ---------------- K4: decoder + residual ----------------
__global__ __launch_bounds__(256, 2) void k_decoder(
    const float4* __restrict__ px4, const float* __restrict__ f,
    const float* __restrict__ yp,
    const float* __restrict__ dw1, const float* __restrict__ db1,
    const float* __restrict__ dw2, const float* __restrict__ db2,
    const float* __restrict__ dw3, const float* __restrict__ db3,
    const float* __restrict__ dw4, const float* __restrict__ db4,
    float* __restrict__ out) {
    int n = blockIdx.x * blockDim.x + threadIdx.x;
    if (n >= N_NODES) return;

    float4 P = px4[n];
    float fn = f[n];
    float in5[5] = {P.x, P.y, P.z, P.w, fn};

    float h1[64];
#pragma unroll
    for (int i = 0; i < 64; i++) {
        float a = db1[i];
#pragma unroll
        for (int k = 0; k < 5; k++) a += dw1[k * 64 + i] * in5[k];
        h1[i] = fmaxf(a, 0.f);
    }

    float h2[64];
#pragma unroll
    for (int jc = 0; jc < 4; jc++) {
        float acc[16];
#pragma unroll
        for (int j = 0; j < 16; j++) acc[j] = db2[jc * 16 + j];
#pragma unroll
        for (int i = 0; i < 64; i++) {
#pragma unroll
            for (int j = 0; j < 16; j++) acc[j] += h1[i] * dw2[i * 64 + jc * 16 + j];
        }
#pragma unroll
        for (int j = 0; j < 16; j++) h2[jc * 16 + j] = fmaxf(acc[j], 0.f);
    }

    float o = db4[0];
#pragma unroll
    for (int jc = 0; jc < 4; jc++) {
        float acc[16];
#pragma unroll
        for (int j = 0; j < 16; j++) acc[j] = db3[jc * 16 + j];
#pragma unroll
        for (int i = 0; i < 64; i++) {
#pragma unroll
            for (int j = 0; j < 16; j++) acc[j] += h2[i] * dw3[i * 64 + jc * 16 + j];
        }
#pragma unroll
        for (int j = 0; j < 16; j++) o += fmaxf(acc[j], 0.f) * dw4[jc * 16 + j];
    }
    out[n] = yp[n] + o;
}

extern "C" void kernel_launch(void* const* d_in, const int* in_sizes, int n_in,
                              void* d_out, int out_size, void* d_ws, size_t ws_size,
                              hipStream_t stream) {
    const float* X    = (const float*)d_in[0];
    const float* yp   = (const float*)d_in[1];
    const int*   edge = (const int*)d_in[2];
    const float *ew1 = (const float*)d_in[3],  *eb1 = (const float*)d_in[4];
    const float *ew2 = (const float*)d_in[5],  *eb2 = (const float*)d_in[6];
    const float *ew3 = (const float*)d_in[7],  *eb3 = (const float*)d_in[8];
    const float *nw1 = (const float*)d_in[9],  *nb1 = (const float*)d_in[10];
    const float *nw2 = (const float*)d_in[11], *nb2 = (const float*)d_in[12];
    const float *nw3 = (const float*)d_in[13], *nb3 = (const float*)d_in[14];
    const float *dw1 = (const float*)d_in[15], *db1 = (const float*)d_in[16];
    const float *dw2 = (const float*)d_in[17], *db2 = (const float*)d_in[18];
    const float *dw3 = (const float*)d_in[19], *db3 = (const float*)d_in[20];
    const float *dw4 = (const float*)d_in[21], *db4 = (const float*)d_in[22];
    float* out = (float*)d_out;

    char* p = (char*)d_ws;
    auto carve = [&](size_t bytes) {
        char* r = p;
        p += (bytes + 255) & ~(size_t)255;
        return r;
    };
    int2*   sd   = (int2*)  carve(sizeof(int2)   * N_EDGES);
    float4* dnrm = (float4*)carve(sizeof(float4) * N_EDGES);
    float4* ea   = (float4*)carve(sizeof(float4) * N_EDGES);
    float4* px4  = (float4*)carve(sizeof(float4) * N_NODES);
    float*  f    = (float*) carve(sizeof(float)  * N_NODES);
    float*  cnt  = (float*) carve(sizeof(float)  * N_NODES);
    float*  aggr = (float*) carve(sizeof(float)  * 3 * N_NODES);

    const int nb_n = (N_NODES + 255) / 256;
    const int nb_e = (N_EDGES + 255) / 256;  // 3125, exact

    hipMemsetAsync(cnt, 0, sizeof(float) * N_NODES, stream);
    k_node_init<<<nb_n, 256, 0, stream>>>(X, yp, px4, f);
    k_edge_init<<<nb_e, 256, 0, stream>>>(edge, px4, yp, sd, dnrm, ea, cnt);

    for (int it = 0; it < 3; ++it) {
        hipMemsetAsync(aggr, 0, sizeof(float) * 3 * N_NODES, stream);
        k_edge_mlp<<<nb_e, 256, 0, stream>>>(sd, dnrm, ea, f,
                                             ew1, eb1, ew2, eb2, ew3, eb3, aggr);
        k_node_mlp<<<nb_n, 256, 0, stream>>>(px4, f, aggr, cnt,
                                             nw1, nb1, nw2, nb2, nw3, nb3);
    }
    k_decoder<<<nb_n, 256, 0, stream>>>(px4, f, yp,
                                        dw1, db1, dw2, db2, dw3, db3, dw4, db4, out);
}

// Round 6
// 531.973 us; speedup vs baseline: 1.7607x; 1.4285x over previous
//
#include <hip/hip_runtime.h>
#include <math.h>

#define N_NODES 50000
#define N_EDGES 800000
#define EPS 1e-12f
#define SCAN_NB 196  // ceil(50000/256)

typedef __attribute__((ext_vector_type(8))) short bf16x8;
typedef __attribute__((ext_vector_type(4))) float f32x4;

__device__ inline unsigned pk_bf16(float a, float b) {
    unsigned ua = __float_as_uint(a), ub = __float_as_uint(b);
    ua = (ua + 0x7FFFu + ((ua >> 16) & 1u)) >> 16;
    ub = (ub + 0x7FFFu + ((ub >> 16) & 1u)) >> 16;
    return ua | (ub << 16);
}
__device__ inline unsigned short bf16_1(float a) {
    unsigned ua = __float_as_uint(a);
    return (unsigned short)((ua + 0x7FFFu + ((ua >> 16) & 1u)) >> 16);
}

// ---------------- K0: per-node precompute ----------------
__global__ void k_node_init(const float* __restrict__ X, const float* __restrict__ yp,
                            float4* __restrict__ px4, float* __restrict__ f) {
    int n = blockIdx.x * blockDim.x + threadIdx.x;
    if (n < N_NODES) {
        px4[n] = make_float4(X[n * 6 + 0], X[n * 6 + 1], X[n * 6 + 2], X[n * 6 + 4]);
        f[n] = yp[n];
    }
}

// ---------------- counting sort by dst ----------------
__global__ void k_hist(const int* __restrict__ edge, int* __restrict__ cnt) {
    int e = blockIdx.x * blockDim.x + threadIdx.x;
    if (e < N_EDGES) atomicAdd(&cnt[edge[N_EDGES + e]], 1);
}

__global__ void k_scan1(const int* __restrict__ cnt, int* __restrict__ tmp,
                        int* __restrict__ bsum) {
    __shared__ int s[256];
    int t = threadIdx.x, i = blockIdx.x * 256 + t;
    int v = (i < N_NODES) ? cnt[i] : 0;
    s[t] = v;
    __syncthreads();
    for (int off = 1; off < 256; off <<= 1) {
        int x = (t >= off) ? s[t - off] : 0;
        __syncthreads();
        s[t] += x;
        __syncthreads();
    }
    if (i < N_NODES) tmp[i] = s[t];  // inclusive within block
    if (t == 255) bsum[blockIdx.x] = s[255];
}

__global__ void k_scan2(const int* __restrict__ bsum, int* __restrict__ boff) {
    __shared__ int s[256];
    int t = threadIdx.x;
    int v = (t < SCAN_NB) ? bsum[t] : 0;
    s[t] = v;
    __syncthreads();
    for (int off = 1; off < 256; off <<= 1) {
        int x = (t >= off) ? s[t - off] : 0;
        __syncthreads();
        s[t] += x;
        __syncthreads();
    }
    if (t < SCAN_NB) boff[t] = s[t] - v;  // exclusive block offset
}

__global__ void k_scan3(const int* __restrict__ tmp, const int* __restrict__ boff,
                        int* __restrict__ rowptr) {
    int i = blockIdx.x * 256 + threadIdx.x;
    if (i < N_NODES) rowptr[i + 1] = tmp[i] + boff[blockIdx.x];
    if (i == 0) rowptr[0] = 0;
}

__global__ void k_scatter(const int* __restrict__ edge, const int* __restrict__ rowptr,
                          int* __restrict__ fill, int2* __restrict__ sd) {
    int e = blockIdx.x * blockDim.x + threadIdx.x;
    if (e < N_EDGES) {
        int s = edge[e], d = edge[N_EDGES + e];
        int pos = rowptr[d] + atomicAdd(&fill[d], 1);
        sd[pos] = make_int2(s, d);
    }
}

// ---------------- K1: per-edge precompute (sorted order, no atomics) --------
__global__ void k_edge_init(const int2* __restrict__ sd,
                            const float4* __restrict__ px4,
                            const float* __restrict__ yp,
                            float4* __restrict__ dnrm, float4* __restrict__ ea) {
    int e = blockIdx.x * blockDim.x + threadIdx.x;
    if (e < N_EDGES) {
        int2 SD = sd[e];
        float4 ps = px4[SD.x], pd = px4[SD.y];
        float dx = pd.x - ps.x, dy = pd.y - ps.y, dz = pd.z - ps.z;
        float nrm = sqrtf(dx * dx + dy * dy + dz * dz + EPS);
        dnrm[e] = make_float4(dx, dy, dz, nrm);
        float fr = yp[SD.y] - yp[SD.x];
        ea[e] = make_float4(fr * dx, fr * dy, fr * dz, 0.f);
    }
}

// ---------------- K2: edge MLP via bf16 MFMA (no atomics) ----------------
#define W1OFF 0
#define W2OFF 4096
#define W3OFF 13312
#define BUFOFF 15616
#define RS 144

__global__ __launch_bounds__(256, 2) void k_edge_mlp(
    const int2* __restrict__ sd, const float4* __restrict__ dnrm,
    float4* __restrict__ ea, const float* __restrict__ f,
    const float* __restrict__ ew1, const float* __restrict__ eb1,
    const float* __restrict__ ew2, const float* __restrict__ eb2,
    const float* __restrict__ ew3, const float* __restrict__ eb3) {
    __shared__ __align__(16) char smem[15616 + 4 * 64 * RS];
    const int t = threadIdx.x;
    const int lane = t & 63, wave = t >> 6;
    const int c = lane & 15, q = lane >> 4;

    {
        int n = t & 63, kg = t >> 6;
        unsigned pk[4];
#pragma unroll
        for (int i = 0; i < 4; i++) {
            int k0 = kg * 8 + i * 2;
            float v0 = (k0 < 9) ? ew1[k0 * 64 + n] : 0.f;
            float v1 = (k0 + 1 < 9) ? ew1[(k0 + 1) * 64 + n] : 0.f;
            pk[i] = pk_bf16(v0, v1);
        }
        *(uint4*)(smem + W1OFF + n * 64 + kg * 16) =
            make_uint4(pk[0], pk[1], pk[2], pk[3]);

        unsigned pk2[8];
#pragma unroll
        for (int i = 0; i < 8; i++) {
            int k0 = kg * 16 + i * 2;
            pk2[i] = pk_bf16(ew2[k0 * 64 + n], ew2[(k0 + 1) * 64 + n]);
        }
        *(uint4*)(smem + W2OFF + n * RS + kg * 32) =
            make_uint4(pk2[0], pk2[1], pk2[2], pk2[3]);
        *(uint4*)(smem + W2OFF + n * RS + kg * 32 + 16) =
            make_uint4(pk2[4], pk2[5], pk2[6], pk2[7]);

        int n3 = t & 15, kg3 = t >> 4;
        unsigned pk3[2];
#pragma unroll
        for (int i = 0; i < 2; i++) {
            int k0 = kg3 * 4 + i * 2;
            float v0 = (n3 < 3) ? ew3[k0 * 3 + n3] : 0.f;
            float v1 = (n3 < 3) ? ew3[(k0 + 1) * 3 + n3] : 0.f;
            pk3[i] = pk_bf16(v0, v1);
        }
        *(uint2*)(smem + W3OFF + n3 * RS + kg3 * 8) = make_uint2(pk3[0], pk3[1]);
    }

    char* mybuf = smem + BUFOFF + wave * (64 * RS);
    const int e = blockIdx.x * 256 + t;
    int2 SD = sd[e];
    float4 DN = dnrm[e];
    float4 EA = ea[e];
    float fs = f[SD.x], fd = f[SD.y];
    {
        char* row = mybuf + lane * RS;
        *(uint4*)(row) = make_uint4(pk_bf16(DN.x, DN.y), pk_bf16(DN.z, DN.w),
                                    pk_bf16(EA.x, EA.y), pk_bf16(EA.z, fs));
        *(uint4*)(row + 16) = make_uint4(pk_bf16(fd, 0.f), 0u, 0u, 0u);
        *(uint4*)(row + 32) = make_uint4(0u, 0u, 0u, 0u);
        *(uint4*)(row + 48) = make_uint4(0u, 0u, 0u, 0u);
    }
    __syncthreads();

    // GEMM1: [64e,32k] x [32k,64n]
    {
        bf16x8 A1[4], B1[4];
#pragma unroll
        for (int mt = 0; mt < 4; mt++)
            A1[mt] = *(bf16x8*)(mybuf + (mt * 16 + c) * RS + q * 16);
#pragma unroll
        for (int nt = 0; nt < 4; nt++)
            B1[nt] = *(bf16x8*)(smem + W1OFF + (nt * 16 + c) * 64 + q * 16);
        f32x4 acc[16];
#pragma unroll
        for (int nt = 0; nt < 4; nt++) {
            float b = eb1[nt * 16 + c];
#pragma unroll
            for (int mt = 0; mt < 4; mt++) acc[mt * 4 + nt] = (f32x4){b, b, b, b};
        }
#pragma unroll
        for (int mt = 0; mt < 4; mt++)
#pragma unroll
            for (int nt = 0; nt < 4; nt++)
                acc[mt * 4 + nt] = __builtin_amdgcn_mfma_f32_16x16x32_bf16(
                    A1[mt], B1[nt], acc[mt * 4 + nt], 0, 0, 0);
#pragma unroll
        for (int mt = 0; mt < 4; mt++)
#pragma unroll
            for (int nt = 0; nt < 4; nt++)
#pragma unroll
                for (int r = 0; r < 4; r++)
                    *(unsigned short*)(mybuf + (mt * 16 + q * 4 + r) * RS +
                                       (nt * 16 + c) * 2) =
                        bf16_1(fmaxf(acc[mt * 4 + nt][r], 0.f));
    }

    // GEMM2 + GEMM3 fused per M-tile
    bf16x8 B2[8], B3[2];
#pragma unroll
    for (int nt = 0; nt < 4; nt++)
#pragma unroll
        for (int ks = 0; ks < 2; ks++)
            B2[nt * 2 + ks] =
                *(bf16x8*)(smem + W2OFF + (nt * 16 + c) * RS + ks * 64 + q * 16);
#pragma unroll
    for (int ks = 0; ks < 2; ks++)
        B3[ks] = *(bf16x8*)(smem + W3OFF + c * RS + ks * 64 + q * 16);
    float b3i = (c < 3) ? eb3[c] : 0.f;

#pragma unroll
    for (int mt = 0; mt < 4; mt++) {
        bf16x8 A2[2];
#pragma unroll
        for (int ks = 0; ks < 2; ks++)
            A2[ks] = *(bf16x8*)(mybuf + (mt * 16 + c) * RS + ks * 64 + q * 16);
        f32x4 a2[4];
#pragma unroll
        for (int nt = 0; nt < 4; nt++) {
            float b = eb2[nt * 16 + c];
            a2[nt] = (f32x4){b, b, b, b};
            a2[nt] = __builtin_amdgcn_mfma_f32_16x16x32_bf16(A2[0], B2[nt * 2 + 0],
                                                             a2[nt], 0, 0, 0);
            a2[nt] = __builtin_amdgcn_mfma_f32_16x16x32_bf16(A2[1], B2[nt * 2 + 1],
                                                             a2[nt], 0, 0, 0);
        }
#pragma unroll
        for (int nt = 0; nt < 4; nt++)
#pragma unroll
            for (int r = 0; r < 4; r++)
                *(unsigned short*)(mybuf + (mt * 16 + q * 4 + r) * RS +
                                   (nt * 16 + c) * 2) =
                    bf16_1(fmaxf(a2[nt][r], 0.f));
        bf16x8 A3[2];
#pragma unroll
        for (int ks = 0; ks < 2; ks++)
            A3[ks] = *(bf16x8*)(mybuf + (mt * 16 + c) * RS + ks * 64 + q * 16);
        f32x4 a3 = (f32x4){b3i, b3i, b3i, b3i};
        a3 = __builtin_amdgcn_mfma_f32_16x16x32_bf16(A3[0], B3[0], a3, 0, 0, 0);
        a3 = __builtin_amdgcn_mfma_f32_16x16x32_bf16(A3[1], B3[1], a3, 0, 0, 0);
        if (c < 3) {
#pragma unroll
            for (int r = 0; r < 4; r++)
                *(float*)(mybuf + (mt * 16 + q * 4 + r) * RS + 128 + c * 4) = a3[r];
        }
    }

    float4 o = *(float4*)(mybuf + lane * RS + 128);
    ea[e] = make_float4(EA.x + o.x, EA.y + o.y, EA.z + o.z, 0.f);
}

// ---------------- K3: segment-mean + node MLP ----------------
__global__ __launch_bounds__(256, 2) void k_node_mlp(
    const float4* __restrict__ px4, float* __restrict__ f,
    const float4* __restrict__ ea, const int* __restrict__ rowptr,
    const float* __restrict__ nw1, const float* __restrict__ nb1,
    const float* __restrict__ nw2, const float* __restrict__ nb2,
    const float* __restrict__ nw3, const float* __restrict__ nb3) {
    int n = blockIdx.x * blockDim.x + threadIdx.x;
    if (n >= N_NODES) return;

    int b0 = rowptr[n], b1 = rowptr[n + 1];
    float a0 = 0.f, a1 = 0.f, a2 = 0.f;
    for (int p = b0; p < b1; p++) {
        float4 v = ea[p];
        a0 += v.x; a1 += v.y; a2 += v.z;
    }
    float inv = 1.0f / fmaxf((float)(b1 - b0), 1.0f);

    float4 P = px4[n];
    float fn = f[n];
    float in5[5] = {P.w, fn, a0 * inv, a1 * inv, a2 * inv};

    float h1[64];
#pragma unroll
    for (int i = 0; i < 64; i++) {
        float a = nb1[i];
#pragma unroll
        for (int k = 0; k < 5; k++) a += nw1[k * 64 + i] * in5[k];
        h1[i] = fmaxf(a, 0.f);
    }

    float o = nb3[0];
#pragma unroll
    for (int jc = 0; jc < 4; jc++) {
        float acc[16];
#pragma unroll
        for (int j = 0; j < 16; j++) acc[j] = nb2[jc * 16 + j];
#pragma unroll
        for (int i = 0; i < 64; i++) {
#pragma unroll
            for (int j = 0; j < 16; j++) acc[j] += h1[i] * nw2[i * 64 + jc * 16 + j];
        }
#pragma unroll
        for (int j = 0; j < 16; j++) o += fmaxf(acc[j], 0.f) * nw3[jc * 16 + j];
    }
    f[n] = fn + o;
}

// ---------------- K4: decoder + residual ----------------
__global__ __launch_bounds__(256, 2) void k_decoder(
    const float4* __restrict__ px4, const float* __restrict__ f,
    const float* __restrict__ yp,
    const float* __restrict__ dw1, const float* __restrict__ db1,
    const float* __restrict__ dw2, const float* __restrict__ db2,
    const float* __restrict__ dw3, const float* __restrict__ db3,
    const float* __restrict__ dw4, const float* __restrict__ db4,
    float* __restrict__ out) {
    int n = blockIdx.x * blockDim.x + threadIdx.x;
    if (n >= N_NODES) return;

    float4 P = px4[n];
    float fn = f[n];
    float in5[5] = {P.x, P.y, P.z, P.w, fn};

    float h1[64];
#pragma unroll
    for (int i = 0; i < 64; i++) {
        float a = db1[i];
#pragma unroll
        for (int k = 0; k < 5; k++) a += dw1[k * 64 + i] * in5[k];
        h1[i] = fmaxf(a, 0.f);
    }

    float h2[64];
#pragma unroll
    for (int jc = 0; jc < 4; jc++) {
        float acc[16];
#pragma unroll
        for (int j = 0; j < 16; j++) acc[j] = db2[jc * 16 + j];
#pragma unroll
        for (int i = 0; i < 64; i++) {
#pragma unroll
            for (int j = 0; j < 16; j++) acc[j] += h1[i] * dw2[i * 64 + jc * 16 + j];
        }
#pragma unroll
        for (int j = 0; j < 16; j++) h2[jc * 16 + j] = fmaxf(acc[j], 0.f);
    }

    float o = db4[0];
#pragma unroll
    for (int jc = 0; jc < 4; jc++) {
        float acc[16];
#pragma unroll
        for (int j = 0; j < 16; j++) acc[j] = db3[jc * 16 + j];
#pragma unroll
        for (int i = 0; i < 64; i++) {
#pragma unroll
            for (int j = 0; j < 16; j++) acc[j] += h2[i] * dw3[i * 64 + jc * 16 + j];
        }
#pragma unroll
        for (int j = 0; j < 16; j++) o += fmaxf(acc[j], 0.f) * dw4[jc * 16 + j];
    }
    out[n] = yp[n] + o;
}

extern "C" void kernel_launch(void* const* d_in, const int* in_sizes, int n_in,
                              void* d_out, int out_size, void* d_ws, size_t ws_size,
                              hipStream_t stream) {
    const float* X    = (const float*)d_in[0];
    const float* yp   = (const float*)d_in[1];
    const int*   edge = (const int*)d_in[2];
    const float *ew1 = (const float*)d_in[3],  *eb1 = (const float*)d_in[4];
    const float *ew2 = (const float*)d_in[5],  *eb2 = (const float*)d_in[6];
    const float *ew3 = (const float*)d_in[7],  *eb3 = (const float*)d_in[8];
    const float *nw1 = (const float*)d_in[9],  *nb1 = (const float*)d_in[10];
    const float *nw2 = (const float*)d_in[11], *nb2 = (const float*)d_in[12];
    const float *nw3 = (const float*)d_in[13], *nb3 = (const float*)d_in[14];
    const float *dw1 = (const float*)d_in[15], *db1 = (const float*)d_in[16];
    const float *dw2 = (const float*)d_in[17], *db2 = (const float*)d_in[18];
    const float *dw3 = (const float*)d_in[19], *db3 = (const float*)d_in[20];
    const float *dw4 = (const float*)d_in[21], *db4 = (const float*)d_in[22];
    float* out = (float*)d_out;

    char* p = (char*)d_ws;
    auto carve = [&](size_t bytes) {
        char* r = p;
        p += (bytes + 255) & ~(size_t)255;
        return r;
    };
    int2*   sd     = (int2*)  carve(sizeof(int2)   * N_EDGES);
    float4* dnrm   = (float4*)carve(sizeof(float4) * N_EDGES);
    float4* ea     = (float4*)carve(sizeof(float4) * N_EDGES);
    float4* px4    = (float4*)carve(sizeof(float4) * N_NODES);
    float*  f      = (float*) carve(sizeof(float)  * N_NODES);
    int*    cnt_i  = (int*)   carve(sizeof(int)    * N_NODES);
    int*    fill   = (int*)   carve(sizeof(int)    * N_NODES);
    int*    tmp    = (int*)   carve(sizeof(int)    * N_NODES);
    int*    rowptr = (int*)   carve(sizeof(int)    * (N_NODES + 1));
    int*    bsum   = (int*)   carve(sizeof(int)    * 256);
    int*    boff   = (int*)   carve(sizeof(int)    * 256);

    const int nb_n = SCAN_NB;                 // 196
    const int nb_e = (N_EDGES + 255) / 256;   // 3125, exact

    hipMemsetAsync(cnt_i, 0, sizeof(int) * N_NODES, stream);
    hipMemsetAsync(fill, 0, sizeof(int) * N_NODES, stream);
    k_node_init<<<nb_n, 256, 0, stream>>>(X, yp, px4, f);
    k_hist<<<nb_e, 256, 0, stream>>>(edge, cnt_i);
    k_scan1<<<nb_n, 256, 0, stream>>>(cnt_i, tmp, bsum);
    k_scan2<<<1, 256, 0, stream>>>(bsum, boff);
    k_scan3<<<nb_n, 256, 0, stream>>>(tmp, boff, rowptr);
    k_scatter<<<nb_e, 256, 0, stream>>>(edge, rowptr, fill, sd);
    k_edge_init<<<nb_e, 256, 0, stream>>>(sd, px4, yp, dnrm, ea);

    for (int it = 0; it < 3; ++it) {
        k_edge_mlp<<<nb_e, 256, 0, stream>>>(sd, dnrm, ea, f,
                                             ew1, eb1, ew2, eb2, ew3, eb3);
        k_node_mlp<<<nb_n, 256, 0, stream>>>(px4, f, ea, rowptr,
                                             nw1, nb1, nw2, nb2, nw3, nb3);
    }
    k_decoder<<<nb_n, 256, 0, stream>>>(px4, f, yp,
                                        dw1, db1, dw2, db2, dw3, db3, dw4, db4, out);
}

// Round 7
// 356.913 us; speedup vs baseline: 2.6243x; 1.4905x over previous
//
#include <hip/hip_runtime.h>
#include <math.h>

#define N_NODES 50000
#define N_EDGES 800000
#define EPS 1e-12f
#define SCAN_NB 196  // ceil(50000/256)

typedef __attribute__((ext_vector_type(8))) short bf16x8;
typedef __attribute__((ext_vector_type(4))) float f32x4;

__device__ inline unsigned pk_bf16(float a, float b) {
    unsigned ua = __float_as_uint(a), ub = __float_as_uint(b);
    ua = (ua + 0x7FFFu + ((ua >> 16) & 1u)) >> 16;
    ub = (ub + 0x7FFFu + ((ub >> 16) & 1u)) >> 16;
    return ua | (ub << 16);
}
__device__ inline unsigned short bf16_1(float a) {
    unsigned ua = __float_as_uint(a);
    return (unsigned short)((ua + 0x7FFFu + ((ua >> 16) & 1u)) >> 16);
}

// ---------------- K0: per-node precompute ----------------
__global__ void k_node_init(const float* __restrict__ X, const float* __restrict__ yp,
                            float4* __restrict__ px4, float* __restrict__ f) {
    int n = blockIdx.x * blockDim.x + threadIdx.x;
    if (n < N_NODES) {
        px4[n] = make_float4(X[n * 6 + 0], X[n * 6 + 1], X[n * 6 + 2], X[n * 6 + 4]);
        f[n] = yp[n];
    }
}

// ---------------- counting sort by dst ----------------
__global__ void k_hist(const int* __restrict__ edge, int* __restrict__ cnt) {
    int e = blockIdx.x * blockDim.x + threadIdx.x;
    if (e < N_EDGES) atomicAdd(&cnt[edge[N_EDGES + e]], 1);
}

__global__ void k_scan1(const int* __restrict__ cnt, int* __restrict__ tmp,
                        int* __restrict__ bsum) {
    __shared__ int s[256];
    int t = threadIdx.x, i = blockIdx.x * 256 + t;
    int v = (i < N_NODES) ? cnt[i] : 0;
    s[t] = v;
    __syncthreads();
    for (int off = 1; off < 256; off <<= 1) {
        int x = (t >= off) ? s[t - off] : 0;
        __syncthreads();
        s[t] += x;
        __syncthreads();
    }
    if (i < N_NODES) tmp[i] = s[t];
    if (t == 255) bsum[blockIdx.x] = s[255];
}

__global__ void k_scan2(const int* __restrict__ bsum, int* __restrict__ boff) {
    __shared__ int s[256];
    int t = threadIdx.x;
    int v = (t < SCAN_NB) ? bsum[t] : 0;
    s[t] = v;
    __syncthreads();
    for (int off = 1; off < 256; off <<= 1) {
        int x = (t >= off) ? s[t - off] : 0;
        __syncthreads();
        s[t] += x;
        __syncthreads();
    }
    if (t < SCAN_NB) boff[t] = s[t] - v;
}

__global__ void k_scan3(const int* __restrict__ tmp, const int* __restrict__ boff,
                        int* __restrict__ rowptr) {
    int i = blockIdx.x * 256 + threadIdx.x;
    if (i < N_NODES) rowptr[i + 1] = tmp[i] + boff[blockIdx.x];
    if (i == 0) rowptr[0] = 0;
}

__global__ void k_scatter(const int* __restrict__ edge, const int* __restrict__ rowptr,
                          int* __restrict__ fill, int2* __restrict__ sd) {
    int e = blockIdx.x * blockDim.x + threadIdx.x;
    if (e < N_EDGES) {
        int s = edge[e], d = edge[N_EDGES + e];
        int pos = rowptr[d] + atomicAdd(&fill[d], 1);
        sd[pos] = make_int2(s, d);
    }
}

// ---------------- K1: per-edge precompute (sorted order) --------
__global__ void k_edge_init(const int2* __restrict__ sd,
                            const float4* __restrict__ px4,
                            const float* __restrict__ yp,
                            float4* __restrict__ dnrm, float4* __restrict__ ea) {
    int e = blockIdx.x * blockDim.x + threadIdx.x;
    if (e < N_EDGES) {
        int2 SD = sd[e];
        float4 ps = px4[SD.x], pd = px4[SD.y];
        float dx = pd.x - ps.x, dy = pd.y - ps.y, dz = pd.z - ps.z;
        float nrm = sqrtf(dx * dx + dy * dy + dz * dz + EPS);
        dnrm[e] = make_float4(dx, dy, dz, nrm);
        float fr = yp[SD.y] - yp[SD.x];
        ea[e] = make_float4(fr * dx, fr * dy, fr * dz, 0.f);
    }
}

// ---------------- K2: edge MLP via bf16 MFMA (unchanged from R6) ------------
#define W1OFF 0
#define W2OFF 4096
#define W3OFF 13312
#define BUFOFF 15616
#define RS 144

__global__ __launch_bounds__(256, 2) void k_edge_mlp(
    const int2* __restrict__ sd, const float4* __restrict__ dnrm,
    float4* __restrict__ ea, const float* __restrict__ f,
    const float* __restrict__ ew1, const float* __restrict__ eb1,
    const float* __restrict__ ew2, const float* __restrict__ eb2,
    const float* __restrict__ ew3, const float* __restrict__ eb3) {
    __shared__ __align__(16) char smem[15616 + 4 * 64 * RS];
    const int t = threadIdx.x;
    const int lane = t & 63, wave = t >> 6;
    const int c = lane & 15, q = lane >> 4;

    {
        int n = t & 63, kg = t >> 6;
        unsigned pk[4];
#pragma unroll
        for (int i = 0; i < 4; i++) {
            int k0 = kg * 8 + i * 2;
            float v0 = (k0 < 9) ? ew1[k0 * 64 + n] : 0.f;
            float v1 = (k0 + 1 < 9) ? ew1[(k0 + 1) * 64 + n] : 0.f;
            pk[i] = pk_bf16(v0, v1);
        }
        *(uint4*)(smem + W1OFF + n * 64 + kg * 16) =
            make_uint4(pk[0], pk[1], pk[2], pk[3]);

        unsigned pk2[8];
#pragma unroll
        for (int i = 0; i < 8; i++) {
            int k0 = kg * 16 + i * 2;
            pk2[i] = pk_bf16(ew2[k0 * 64 + n], ew2[(k0 + 1) * 64 + n]);
        }
        *(uint4*)(smem + W2OFF + n * RS + kg * 32) =
            make_uint4(pk2[0], pk2[1], pk2[2], pk2[3]);
        *(uint4*)(smem + W2OFF + n * RS + kg * 32 + 16) =
            make_uint4(pk2[4], pk2[5], pk2[6], pk2[7]);

        int n3 = t & 15, kg3 = t >> 4;
        unsigned pk3[2];
#pragma unroll
        for (int i = 0; i < 2; i++) {
            int k0 = kg3 * 4 + i * 2;
            float v0 = (n3 < 3) ? ew3[k0 * 3 + n3] : 0.f;
            float v1 = (n3 < 3) ? ew3[(k0 + 1) * 3 + n3] : 0.f;
            pk3[i] = pk_bf16(v0, v1);
        }
        *(uint2*)(smem + W3OFF + n3 * RS + kg3 * 8) = make_uint2(pk3[0], pk3[1]);
    }

    char* mybuf = smem + BUFOFF + wave * (64 * RS);
    const int e = blockIdx.x * 256 + t;
    int2 SD = sd[e];
    float4 DN = dnrm[e];
    float4 EA = ea[e];
    float fs = f[SD.x], fd = f[SD.y];
    {
        char* row = mybuf + lane * RS;
        *(uint4*)(row) = make_uint4(pk_bf16(DN.x, DN.y), pk_bf16(DN.z, DN.w),
                                    pk_bf16(EA.x, EA.y), pk_bf16(EA.z, fs));
        *(uint4*)(row + 16) = make_uint4(pk_bf16(fd, 0.f), 0u, 0u, 0u);
        *(uint4*)(row + 32) = make_uint4(0u, 0u, 0u, 0u);
        *(uint4*)(row + 48) = make_uint4(0u, 0u, 0u, 0u);
    }
    __syncthreads();

    {
        bf16x8 A1[4], B1[4];
#pragma unroll
        for (int mt = 0; mt < 4; mt++)
            A1[mt] = *(bf16x8*)(mybuf + (mt * 16 + c) * RS + q * 16);
#pragma unroll
        for (int nt = 0; nt < 4; nt++)
            B1[nt] = *(bf16x8*)(smem + W1OFF + (nt * 16 + c) * 64 + q * 16);
        f32x4 acc[16];
#pragma unroll
        for (int nt = 0; nt < 4; nt++) {
            float b = eb1[nt * 16 + c];
#pragma unroll
            for (int mt = 0; mt < 4; mt++) acc[mt * 4 + nt] = (f32x4){b, b, b, b};
        }
#pragma unroll
        for (int mt = 0; mt < 4; mt++)
#pragma unroll
            for (int nt = 0; nt < 4; nt++)
                acc[mt * 4 + nt] = __builtin_amdgcn_mfma_f32_16x16x32_bf16(
                    A1[mt], B1[nt], acc[mt * 4 + nt], 0, 0, 0);
#pragma unroll
        for (int mt = 0; mt < 4; mt++)
#pragma unroll
            for (int nt = 0; nt < 4; nt++)
#pragma unroll
                for (int r = 0; r < 4; r++)
                    *(unsigned short*)(mybuf + (mt * 16 + q * 4 + r) * RS +
                                       (nt * 16 + c) * 2) =
                        bf16_1(fmaxf(acc[mt * 4 + nt][r], 0.f));
    }

    bf16x8 B2[8], B3[2];
#pragma unroll
    for (int nt = 0; nt < 4; nt++)
#pragma unroll
        for (int ks = 0; ks < 2; ks++)
            B2[nt * 2 + ks] =
                *(bf16x8*)(smem + W2OFF + (nt * 16 + c) * RS + ks * 64 + q * 16);
#pragma unroll
    for (int ks = 0; ks < 2; ks++)
        B3[ks] = *(bf16x8*)(smem + W3OFF + c * RS + ks * 64 + q * 16);
    float b3i = (c < 3) ? eb3[c] : 0.f;

#pragma unroll
    for (int mt = 0; mt < 4; mt++) {
        bf16x8 A2[2];
#pragma unroll
        for (int ks = 0; ks < 2; ks++)
            A2[ks] = *(bf16x8*)(mybuf + (mt * 16 + c) * RS + ks * 64 + q * 16);
        f32x4 a2[4];
#pragma unroll
        for (int nt = 0; nt < 4; nt++) {
            float b = eb2[nt * 16 + c];
            a2[nt] = (f32x4){b, b, b, b};
            a2[nt] = __builtin_amdgcn_mfma_f32_16x16x32_bf16(A2[0], B2[nt * 2 + 0],
                                                             a2[nt], 0, 0, 0);
            a2[nt] = __builtin_amdgcn_mfma_f32_16x16x32_bf16(A2[1], B2[nt * 2 + 1],
                                                             a2[nt], 0, 0, 0);
        }
#pragma unroll
        for (int nt = 0; nt < 4; nt++)
#pragma unroll
            for (int r = 0; r < 4; r++)
                *(unsigned short*)(mybuf + (mt * 16 + q * 4 + r) * RS +
                                   (nt * 16 + c) * 2) =
                    bf16_1(fmaxf(a2[nt][r], 0.f));
        bf16x8 A3[2];
#pragma unroll
        for (int ks = 0; ks < 2; ks++)
            A3[ks] = *(bf16x8*)(mybuf + (mt * 16 + c) * RS + ks * 64 + q * 16);
        f32x4 a3 = (f32x4){b3i, b3i, b3i, b3i};
        a3 = __builtin_amdgcn_mfma_f32_16x16x32_bf16(A3[0], B3[0], a3, 0, 0, 0);
        a3 = __builtin_amdgcn_mfma_f32_16x16x32_bf16(A3[1], B3[1], a3, 0, 0, 0);
        if (c < 3) {
#pragma unroll
            for (int r = 0; r < 4; r++)
                *(float*)(mybuf + (mt * 16 + q * 4 + r) * RS + 128 + c * 4) = a3[r];
        }
    }

    float4 o = *(float4*)(mybuf + lane * RS + 128);
    ea[e] = make_float4(EA.x + o.x, EA.y + o.y, EA.z + o.z, 0.f);
}

// ---------------- K3: segment-mean + node MLP via bf16 MFMA ----------------
// Same LDS layout as edge kernel: W1 (k<5 valid), W2, W3out (n=0 valid).
__global__ __launch_bounds__(256, 2) void k_node_mlp(
    const float4* __restrict__ px4, float* __restrict__ f,
    const float4* __restrict__ ea, const int* __restrict__ rowptr,
    const float* __restrict__ nw1, const float* __restrict__ nb1,
    const float* __restrict__ nw2, const float* __restrict__ nb2,
    const float* __restrict__ nw3, const float* __restrict__ nb3) {
    __shared__ __align__(16) char smem[15616 + 4 * 64 * RS];
    const int t = threadIdx.x;
    const int lane = t & 63, wave = t >> 6;
    const int c = lane & 15, q = lane >> 4;

    {
        int n = t & 63, kg = t >> 6;
        unsigned pk[4];
#pragma unroll
        for (int i = 0; i < 4; i++) {
            int k0 = kg * 8 + i * 2;
            float v0 = (k0 < 5) ? nw1[k0 * 64 + n] : 0.f;
            float v1 = (k0 + 1 < 5) ? nw1[(k0 + 1) * 64 + n] : 0.f;
            pk[i] = pk_bf16(v0, v1);
        }
        *(uint4*)(smem + W1OFF + n * 64 + kg * 16) =
            make_uint4(pk[0], pk[1], pk[2], pk[3]);

        unsigned pk2[8];
#pragma unroll
        for (int i = 0; i < 8; i++) {
            int k0 = kg * 16 + i * 2;
            pk2[i] = pk_bf16(nw2[k0 * 64 + n], nw2[(k0 + 1) * 64 + n]);
        }
        *(uint4*)(smem + W2OFF + n * RS + kg * 32) =
            make_uint4(pk2[0], pk2[1], pk2[2], pk2[3]);
        *(uint4*)(smem + W2OFF + n * RS + kg * 32 + 16) =
            make_uint4(pk2[4], pk2[5], pk2[6], pk2[7]);

        int n3 = t & 15, kg3 = t >> 4;
        unsigned pk3[2];
#pragma unroll
        for (int i = 0; i < 2; i++) {
            int k0 = kg3 * 4 + i * 2;
            float v0 = (n3 == 0) ? nw3[k0] : 0.f;
            float v1 = (n3 == 0) ? nw3[k0 + 1] : 0.f;
            pk3[i] = pk_bf16(v0, v1);
        }
        *(uint2*)(smem + W3OFF + n3 * RS + kg3 * 8) = make_uint2(pk3[0], pk3[1]);
    }

    char* mybuf = smem + BUFOFF + wave * (64 * RS);
    const int idx = blockIdx.x * 256 + t;
    const int n = (idx < N_NODES) ? idx : (N_NODES - 1);

    int b0 = rowptr[n], b1 = rowptr[n + 1];
    float a0 = 0.f, a1 = 0.f, a2 = 0.f;
    for (int p = b0; p < b1; p++) {
        float4 v = ea[p];
        a0 += v.x; a1 += v.y; a2 += v.z;
    }
    float inv = 1.0f / fmaxf((float)(b1 - b0), 1.0f);
    float4 P = px4[n];
    float fn = f[n];
    {
        char* row = mybuf + lane * RS;
        *(uint4*)(row) = make_uint4(pk_bf16(P.w, fn), pk_bf16(a0 * inv, a1 * inv),
                                    pk_bf16(a2 * inv, 0.f), 0u);
        *(uint4*)(row + 16) = make_uint4(0u, 0u, 0u, 0u);
        *(uint4*)(row + 32) = make_uint4(0u, 0u, 0u, 0u);
        *(uint4*)(row + 48) = make_uint4(0u, 0u, 0u, 0u);
    }
    __syncthreads();

    {
        bf16x8 A1[4], B1[4];
#pragma unroll
        for (int mt = 0; mt < 4; mt++)
            A1[mt] = *(bf16x8*)(mybuf + (mt * 16 + c) * RS + q * 16);
#pragma unroll
        for (int nt = 0; nt < 4; nt++)
            B1[nt] = *(bf16x8*)(smem + W1OFF + (nt * 16 + c) * 64 + q * 16);
        f32x4 acc[16];
#pragma unroll
        for (int nt = 0; nt < 4; nt++) {
            float b = nb1[nt * 16 + c];
#pragma unroll
            for (int mt = 0; mt < 4; mt++) acc[mt * 4 + nt] = (f32x4){b, b, b, b};
        }
#pragma unroll
        for (int mt = 0; mt < 4; mt++)
#pragma unroll
            for (int nt = 0; nt < 4; nt++)
                acc[mt * 4 + nt] = __builtin_amdgcn_mfma_f32_16x16x32_bf16(
                    A1[mt], B1[nt], acc[mt * 4 + nt], 0, 0, 0);
#pragma unroll
        for (int mt = 0; mt < 4; mt++)
#pragma unroll
            for (int nt = 0; nt < 4; nt++)
#pragma unroll
                for (int r = 0; r < 4; r++)
                    *(unsigned short*)(mybuf + (mt * 16 + q * 4 + r) * RS +
                                       (nt * 16 + c) * 2) =
                        bf16_1(fmaxf(acc[mt * 4 + nt][r], 0.f));
    }

    bf16x8 B2[8], B3[2];
#pragma unroll
    for (int nt = 0; nt < 4; nt++)
#pragma unroll
        for (int ks = 0; ks < 2; ks++)
            B2[nt * 2 + ks] =
                *(bf16x8*)(smem + W2OFF + (nt * 16 + c) * RS + ks * 64 + q * 16);
#pragma unroll
    for (int ks = 0; ks < 2; ks++)
        B3[ks] = *(bf16x8*)(smem + W3OFF + c * RS + ks * 64 + q * 16);
    float b3i = (c == 0) ? nb3[0] : 0.f;

#pragma unroll
    for (int mt = 0; mt < 4; mt++) {
        bf16x8 A2[2];
#pragma unroll
        for (int ks = 0; ks < 2; ks++)
            A2[ks] = *(bf16x8*)(mybuf + (mt * 16 + c) * RS + ks * 64 + q * 16);
        f32x4 a2[4];
#pragma unroll
        for (int nt = 0; nt < 4; nt++) {
            float b = nb2[nt * 16 + c];
            a2[nt] = (f32x4){b, b, b, b};
            a2[nt] = __builtin_amdgcn_mfma_f32_16x16x32_bf16(A2[0], B2[nt * 2 + 0],
                                                             a2[nt], 0, 0, 0);
            a2[nt] = __builtin_amdgcn_mfma_f32_16x16x32_bf16(A2[1], B2[nt * 2 + 1],
                                                             a2[nt], 0, 0, 0);
        }
#pragma unroll
        for (int nt = 0; nt < 4; nt++)
#pragma unroll
            for (int r = 0; r < 4; r++)
                *(unsigned short*)(mybuf + (mt * 16 + q * 4 + r) * RS +
                                   (nt * 16 + c) * 2) =
                    bf16_1(fmaxf(a2[nt][r], 0.f));
        bf16x8 A3[2];
#pragma unroll
        for (int ks = 0; ks < 2; ks++)
            A3[ks] = *(bf16x8*)(mybuf + (mt * 16 + c) * RS + ks * 64 + q * 16);
        f32x4 a3 = (f32x4){b3i, b3i, b3i, b3i};
        a3 = __builtin_amdgcn_mfma_f32_16x16x32_bf16(A3[0], B3[0], a3, 0, 0, 0);
        a3 = __builtin_amdgcn_mfma_f32_16x16x32_bf16(A3[1], B3[1], a3, 0, 0, 0);
        if (c == 0) {
#pragma unroll
            for (int r = 0; r < 4; r++)
                *(float*)(mybuf + (mt * 16 + q * 4 + r) * RS + 128) = a3[r];
        }
    }

    float o = *(float*)(mybuf + lane * RS + 128);
    if (idx < N_NODES) f[n] = fn + o;
}

// ---------------- K4: decoder via bf16 MFMA + residual ----------------
#define DW1OFF 0
#define DW2OFF 4096
#define DW3OFF 13312
#define DW4OFF 22528
#define DBUFOFF 24832

__global__ __launch_bounds__(256, 2) void k_decoder(
    const float4* __restrict__ px4, const float* __restrict__ f,
    const float* __restrict__ yp,
    const float* __restrict__ dw1, const float* __restrict__ db1,
    const float* __restrict__ dw2, const float* __restrict__ db2,
    const float* __restrict__ dw3, const float* __restrict__ db3,
    const float* __restrict__ dw4, const float* __restrict__ db4,
    float* __restrict__ out) {
    __shared__ __align__(16) char smem[24832 + 4 * 64 * RS];
    const int t = threadIdx.x;
    const int lane = t & 63, wave = t >> 6;
    const int c = lane & 15, q = lane >> 4;

    {
        int n = t & 63, kg = t >> 6;
        unsigned pk[4];
#pragma unroll
        for (int i = 0; i < 4; i++) {
            int k0 = kg * 8 + i * 2;
            float v0 = (k0 < 5) ? dw1[k0 * 64 + n] : 0.f;
            float v1 = (k0 + 1 < 5) ? dw1[(k0 + 1) * 64 + n] : 0.f;
            pk[i] = pk_bf16(v0, v1);
        }
        *(uint4*)(smem + DW1OFF + n * 64 + kg * 16) =
            make_uint4(pk[0], pk[1], pk[2], pk[3]);

        unsigned pk2[8], pk3b[8];
#pragma unroll
        for (int i = 0; i < 8; i++) {
            int k0 = kg * 16 + i * 2;
            pk2[i] = pk_bf16(dw2[k0 * 64 + n], dw2[(k0 + 1) * 64 + n]);
            pk3b[i] = pk_bf16(dw3[k0 * 64 + n], dw3[(k0 + 1) * 64 + n]);
        }
        *(uint4*)(smem + DW2OFF + n * RS + kg * 32) =
            make_uint4(pk2[0], pk2[1], pk2[2], pk2[3]);
        *(uint4*)(smem + DW2OFF + n * RS + kg * 32 + 16) =
            make_uint4(pk2[4], pk2[5], pk2[6], pk2[7]);
        *(uint4*)(smem + DW3OFF + n * RS + kg * 32) =
            make_uint4(pk3b[0], pk3b[1], pk3b[2], pk3b[3]);
        *(uint4*)(smem + DW3OFF + n * RS + kg * 32 + 16) =
            make_uint4(pk3b[4], pk3b[5], pk3b[6], pk3b[7]);

        int n4 = t & 15, kg4 = t >> 4;
        unsigned pk4[2];
#pragma unroll
        for (int i = 0; i < 2; i++) {
            int k0 = kg4 * 4 + i * 2;
            float v0 = (n4 == 0) ? dw4[k0] : 0.f;
            float v1 = (n4 == 0) ? dw4[k0 + 1] : 0.f;
            pk4[i] = pk_bf16(v0, v1);
        }
        *(uint2*)(smem + DW4OFF + n4 * RS + kg4 * 8) = make_uint2(pk4[0], pk4[1]);
    }

    char* mybuf = smem + DBUFOFF + wave * (64 * RS);
    const int idx = blockIdx.x * 256 + t;
    const int n = (idx < N_NODES) ? idx : (N_NODES - 1);
    float4 P = px4[n];
    float fn = f[n];
    {
        char* row = mybuf + lane * RS;
        *(uint4*)(row) = make_uint4(pk_bf16(P.x, P.y), pk_bf16(P.z, P.w),
                                    pk_bf16(fn, 0.f), 0u);
        *(uint4*)(row + 16) = make_uint4(0u, 0u, 0u, 0u);
        *(uint4*)(row + 32) = make_uint4(0u, 0u, 0u, 0u);
        *(uint4*)(row + 48) = make_uint4(0u, 0u, 0u, 0u);
    }
    __syncthreads();

    {
        bf16x8 A1[4], B1[4];
#pragma unroll
        for (int mt = 0; mt < 4; mt++)
            A1[mt] = *(bf16x8*)(mybuf + (mt * 16 + c) * RS + q * 16);
#pragma unroll
        for (int nt = 0; nt < 4; nt++)
            B1[nt] = *(bf16x8*)(smem + DW1OFF + (nt * 16 + c) * 64 + q * 16);
        f32x4 acc[16];
#pragma unroll
        for (int nt = 0; nt < 4; nt++) {
            float b = db1[nt * 16 + c];
#pragma unroll
            for (int mt = 0; mt < 4; mt++) acc[mt * 4 + nt] = (f32x4){b, b, b, b};
        }
#pragma unroll
        for (int mt = 0; mt < 4; mt++)
#pragma unroll
            for (int nt = 0; nt < 4; nt++)
                acc[mt * 4 + nt] = __builtin_amdgcn_mfma_f32_16x16x32_bf16(
                    A1[mt], B1[nt], acc[mt * 4 + nt], 0, 0, 0);
#pragma unroll
        for (int mt = 0; mt < 4; mt++)
#pragma unroll
            for (int nt = 0; nt < 4; nt++)
#pragma unroll
                for (int r = 0; r < 4; r++)
                    *(unsigned short*)(mybuf + (mt * 16 + q * 4 + r) * RS +
                                       (nt * 16 + c) * 2) =
                        bf16_1(fmaxf(acc[mt * 4 + nt][r], 0.f));
    }

    bf16x8 B2[8], B3[8], B4[2];
#pragma unroll
    for (int nt = 0; nt < 4; nt++)
#pragma unroll
        for (int ks = 0; ks < 2; ks++) {
            B2[nt * 2 + ks] =
                *(bf16x8*)(smem + DW2OFF + (nt * 16 + c) * RS + ks * 64 + q * 16);
            B3[nt * 2 + ks] =
                *(bf16x8*)(smem + DW3OFF + (nt * 16 + c) * RS + ks * 64 + q * 16);
        }
#pragma unroll
    for (int ks = 0; ks < 2; ks++)
        B4[ks] = *(bf16x8*)(smem + DW4OFF + c * RS + ks * 64 + q * 16);
    float b4i = (c == 0) ? db4[0] : 0.f;

#pragma unroll
    for (int mt = 0; mt < 4; mt++) {
        // layer 2
        bf16x8 A2[2];
#pragma unroll
        for (int ks = 0; ks < 2; ks++)
            A2[ks] = *(bf16x8*)(mybuf + (mt * 16 + c) * RS + ks * 64 + q * 16);
        f32x4 a2[4];
#pragma unroll
        for (int nt = 0; nt < 4; nt++) {
            float b = db2[nt * 16 + c];
            a2[nt] = (f32x4){b, b, b, b};
            a2[nt] = __builtin_amdgcn_mfma_f32_16x16x32_bf16(A2[0], B2[nt * 2 + 0],
                                                             a2[nt], 0, 0, 0);
            a2[nt] = __builtin_amdgcn_mfma_f32_16x16x32_bf16(A2[1], B2[nt * 2 + 1],
                                                             a2[nt], 0, 0, 0);
        }
#pragma unroll
        for (int nt = 0; nt < 4; nt++)
#pragma unroll
            for (int r = 0; r < 4; r++)
                *(unsigned short*)(mybuf + (mt * 16 + q * 4 + r) * RS +
                                   (nt * 16 + c) * 2) =
                    bf16_1(fmaxf(a2[nt][r], 0.f));
        // layer 3
        bf16x8 A3[2];
#pragma unroll
        for (int ks = 0; ks < 2; ks++)
            A3[ks] = *(bf16x8*)(mybuf + (mt * 16 + c) * RS + ks * 64 + q * 16);
        f32x4 a3[4];
#pragma unroll
        for (int nt = 0; nt < 4; nt++) {
            float b = db3[nt * 16 + c];
            a3[nt] = (f32x4){b, b, b, b};
            a3[nt] = __builtin_amdgcn_mfma_f32_16x16x32_bf16(A3[0], B3[nt * 2 + 0],
                                                             a3[nt], 0, 0, 0);
            a3[nt] = __builtin_amdgcn_mfma_f32_16x16x32_bf16(A3[1], B3[nt * 2 + 1],
                                                             a3[nt], 0, 0, 0);
        }
#pragma unroll
        for (int nt = 0; nt < 4; nt++)
#pragma unroll
            for (int r = 0; r < 4; r++)
                *(unsigned short*)(mybuf + (mt * 16 + q * 4 + r) * RS +
                                   (nt * 16 + c) * 2) =
                    bf16_1(fmaxf(a3[nt][r], 0.f));
        // layer 4 (64 -> 1)
        bf16x8 A4[2];
#pragma unroll
        for (int ks = 0; ks < 2; ks++)
            A4[ks] = *(bf16x8*)(mybuf + (mt * 16 + c) * RS + ks * 64 + q * 16);
        f32x4 a4 = (f32x4){b4i, b4i, b4i, b4i};
        a4 = __builtin_amdgcn_mfma_f32_16x16x32_bf16(A4[0], B4[0], a4, 0, 0, 0);
        a4 = __builtin_amdgcn_mfma_f32_16x16x32_bf16(A4[1], B4[1], a4, 0, 0, 0);
        if (c == 0) {
#pragma unroll
            for (int r = 0; r < 4; r++)
                *(float*)(mybuf + (mt * 16 + q * 4 + r) * RS + 128) = a4[r];
        }
    }

    float o = *(float*)(mybuf + lane * RS + 128);
    if (idx < N_NODES) out[n] = yp[n] + o;
}

extern "C" void kernel_launch(void* const* d_in, const int* in_sizes, int n_in,
                              void* d_out, int out_size, void* d_ws, size_t ws_size,
                              hipStream_t stream) {
    const float* X    = (const float*)d_in[0];
    const float* yp   = (const float*)d_in[1];
    const int*   edge = (const int*)d_in[2];
    const float *ew1 = (const float*)d_in[3],  *eb1 = (const float*)d_in[4];
    const float *ew2 = (const float*)d_in[5],  *eb2 = (const float*)d_in[6];
    const float *ew3 = (const float*)d_in[7],  *eb3 = (const float*)d_in[8];
    const float *nw1 = (const float*)d_in[9],  *nb1 = (const float*)d_in[10];
    const float *nw2 = (const float*)d_in[11], *nb2 = (const float*)d_in[12];
    const float *nw3 = (const float*)d_in[13], *nb3 = (const float*)d_in[14];
    const float *dw1 = (const float*)d_in[15], *db1 = (const float*)d_in[16];
    const float *dw2 = (const float*)d_in[17], *db2 = (const float*)d_in[18];
    const float *dw3 = (const float*)d_in[19], *db3 = (const float*)d_in[20];
    const float *dw4 = (const float*)d_in[21], *db4 = (const float*)d_in[22];
    float* out = (float*)d_out;

    char* p = (char*)d_ws;
    auto carve = [&](size_t bytes) {
        char* r = p;
        p += (bytes + 255) & ~(size_t)255;
        return r;
    };
    int2*   sd     = (int2*)  carve(sizeof(int2)   * N_EDGES);
    float4* dnrm   = (float4*)carve(sizeof(float4) * N_EDGES);
    float4* ea     = (float4*)carve(sizeof(float4) * N_EDGES);
    float4* px4    = (float4*)carve(sizeof(float4) * N_NODES);
    float*  f      = (float*) carve(sizeof(float)  * N_NODES);
    int*    cnt_i  = (int*)   carve(sizeof(int)    * N_NODES);
    int*    fill   = (int*)   carve(sizeof(int)    * N_NODES);
    int*    tmp    = (int*)   carve(sizeof(int)    * N_NODES);
    int*    rowptr = (int*)   carve(sizeof(int)    * (N_NODES + 1));
    int*    bsum   = (int*)   carve(sizeof(int)    * 256);
    int*    boff   = (int*)   carve(sizeof(int)    * 256);

    const int nb_n = SCAN_NB;                 // 196
    const int nb_e = (N_EDGES + 255) / 256;   // 3125, exact

    hipMemsetAsync(cnt_i, 0, sizeof(int) * N_NODES, stream);
    hipMemsetAsync(fill, 0, sizeof(int) * N_NODES, stream);
    k_node_init<<<nb_n, 256, 0, stream>>>(X, yp, px4, f);
    k_hist<<<nb_e, 256, 0, stream>>>(edge, cnt_i);
    k_scan1<<<nb_n, 256, 0, stream>>>(cnt_i, tmp, bsum);
    k_scan2<<<1, 256, 0, stream>>>(bsum, boff);
    k_scan3<<<nb_n, 256, 0, stream>>>(tmp, boff, rowptr);
    k_scatter<<<nb_e, 256, 0, stream>>>(edge, rowptr, fill, sd);
    k_edge_init<<<nb_e, 256, 0, stream>>>(sd, px4, yp, dnrm, ea);

    for (int it = 0; it < 3; ++it) {
        k_edge_mlp<<<nb_e, 256, 0, stream>>>(sd, dnrm, ea, f,
                                             ew1, eb1, ew2, eb2, ew3, eb3);
        k_node_mlp<<<nb_n, 256, 0, stream>>>(px4, f, ea, rowptr,
                                             nw1, nb1, nw2, nb2, nw3, nb3);
    }
    k_decoder<<<nb_n, 256, 0, stream>>>(px4, f, yp,
                                        dw1, db1, dw2, db2, dw3, db3, dw4, db4, out);
}